// Round 2
// baseline (164.869 us; speedup 1.0000x reference)
//
#include <hip/hip_runtime.h>
#include <hip/hip_bf16.h>
#include <stdint.h>

typedef __attribute__((ext_vector_type(8))) short short8;
typedef __attribute__((ext_vector_type(4))) float f32x4;

#define HD 256

__device__ __forceinline__ ushort f2bf(float f) {
  union { float f; uint32_t u; } x; x.f = f;
  uint32_t r = (x.u + 0x7fffu + ((x.u >> 16) & 1u)) >> 16;
  return (ushort)r;
}

// swizzled index (ushort units) into a [rows][256] bf16 LDS buffer.
// XOR-swizzle per 16B chunk to kill the row-stride-512B bank conflict (G4).
__device__ __forceinline__ int swz(int row, int col) {
  int chunk = (col >> 3) ^ (row & 7);
  return row * 256 + chunk * 8 + (col & 7);
}

// ---------------- prep: bincount + weight bf16 conversion ----------------
__global__ void prep1_kernel(const int* __restrict__ batch, int total_nodes,
                             int* __restrict__ sections,
                             const float* __restrict__ in_proj_w,
                             const float* __restrict__ out_proj_w,
                             const float* __restrict__ d1_w,
                             const float* __restrict__ d2_w,
                             const float* __restrict__ W3_w,
                             ushort* __restrict__ Wv_bf, ushort* __restrict__ Po_bf,
                             ushort* __restrict__ d1_bf, ushort* __restrict__ d2_bf,
                             ushort* __restrict__ W3_bf) {
  int stride = gridDim.x * blockDim.x;
  int t0 = blockIdx.x * blockDim.x + threadIdx.x;
  for (int i = t0; i < total_nodes; i += stride)
    atomicAdd(&sections[batch[i]], 1);
  for (int i = t0; i < HD * HD; i += stride) {
    Wv_bf[i] = f2bf(in_proj_w[2 * HD * HD + i]);
    Po_bf[i] = f2bf(out_proj_w[i]);
    d1_bf[i] = f2bf(d1_w[i]);
    d2_bf[i] = f2bf(d2_w[i]);
  }
  for (int i = t0; i < HD * 2 * HD; i += stride)
    W3_bf[i] = f2bf(W3_w[i]);
}

// ---------------- scan: offsets (exclusive) + last_idx (inclusive-1) -----
__global__ void scan_kernel(const int* __restrict__ seq_len, int* __restrict__ sections,
                            int* __restrict__ offsets, int* __restrict__ last_idx,
                            int nsess) {
  __shared__ int s1[1024];
  __shared__ int s2[1024];
  int t = threadIdx.x;
  int v1 = (t < nsess) ? sections[t] : 0;
  int v2 = (t < nsess) ? seq_len[t] : 0;
  s1[t] = v1; s2[t] = v2;
  for (int d = 1; d < 1024; d <<= 1) {
    __syncthreads();
    int a1 = (t >= d) ? s1[t - d] : 0;
    int a2 = (t >= d) ? s2[t - d] : 0;
    __syncthreads();
    s1[t] += a1; s2[t] += a2;
  }
  __syncthreads();
  if (t < nsess) {
    offsets[t] = s1[t] - v1;     // exclusive cumsum of sections
    last_idx[t] = s2[t] - 1;     // cumsum(sequence_len) - 1
  }
}

// ---------------- one SAN GEMM stage: out = act(in @ W^T + b) ------------
template<bool RELU, bool RESID, bool WACC>
__device__ __forceinline__ void gemm_stage(const ushort* inA, const ushort* __restrict__ Wbf,
                                           const float* __restrict__ bias,
                                           float* accf, ushort* outB) {
  int t = threadIdx.x;
  int lane = t & 63, wid = t >> 6;
  int la = lane & 15, g = lane >> 4;
  int colb = wid * 64;
  f32x4 acc[4] = {{0.f,0.f,0.f,0.f},{0.f,0.f,0.f,0.f},{0.f,0.f,0.f,0.f},{0.f,0.f,0.f,0.f}};
#pragma unroll
  for (int kk = 0; kk < 8; ++kk) {
    short8 a = *(const short8*)&inA[swz(la, kk * 32 + g * 8)];
#pragma unroll
    for (int ct = 0; ct < 4; ++ct) {
      int col = colb + ct * 16 + la;
      short8 b = *(const short8*)&Wbf[col * HD + kk * 32 + g * 8];
      acc[ct] = __builtin_amdgcn_mfma_f32_16x16x32_bf16(a, b, acc[ct], 0, 0, 0);
    }
  }
#pragma unroll
  for (int ct = 0; ct < 4; ++ct) {
    int col = colb + ct * 16 + la;
    float bia = bias[col];
#pragma unroll
    for (int r = 0; r < 4; ++r) {
      int ro = g * 4 + r;
      float v = acc[ct][r] + bia;
      if (RELU) v = fmaxf(v, 0.f);
      if (RESID) v += accf[ro * HD + col];
      if (WACC) accf[ro * HD + col] = v;
      outB[swz(ro, col)] = f2bf(v);
    }
  }
}

// barrier + scheduling fence: stops the compiler hoisting the next stage's
// (loop-invariant) weight loads above this point, which was blowing VGPR
// pressure past 256 and spilling ~600B/thread to scratch (round-1 profile:
// 9.8MB WRITE_SIZE, 150us).
__device__ __forceinline__ void stage_fence() {
  __syncthreads();
  __builtin_amdgcn_sched_barrier(0);
}

// ---------------- v_n + SAN x3 + s_h + y_hat (16 rows / block) -----------
__global__ __launch_bounds__(256) void sh_kernel(
    const float* __restrict__ node_emb, const float* __restrict__ emb_w,
    const float* __restrict__ itemset_len, const float* __restrict__ in_proj_b,
    const float* __restrict__ out_proj_b, const float* __restrict__ d1_b,
    const float* __restrict__ d2_b, const float* __restrict__ W3_b,
    const int* __restrict__ sequence, const int* __restrict__ cue,
    const int* __restrict__ sections, const int* __restrict__ offsets,
    const int* __restrict__ last_idx,
    const ushort* __restrict__ Wv_bf, const ushort* __restrict__ Po_bf,
    const ushort* __restrict__ d1_bf, const ushort* __restrict__ d2_bf,
    const ushort* __restrict__ W3_bf,
    ushort* __restrict__ sh_bf, float* __restrict__ y_hat, int group) {
  __shared__ float accf[16 * HD];
  __shared__ ushort vn_bf[16 * HD];
  __shared__ ushort bufA[16 * HD];
  __shared__ ushort bufB[16 * HD];
  __shared__ float red[16][17];
  int t = threadIdx.x;
  int b0 = blockIdx.x * 16;

  // ---- v_n: gather last-step itemset embedding ----
  {
    int r = t >> 4, cg = t & 15;
    int sess = b0 + r;
    int li = last_idx[sess];
    float inv = 1.0f / itemset_len[li];
    int sec = sections[sess], off = offsets[sess];
    float4 s0 = {0,0,0,0}, s1 = {0,0,0,0}, s2 = {0,0,0,0}, s3 = {0,0,0,0};
    for (int gi = 0; gi < group; ++gi) {
      int sq = sequence[li * group + gi];
      if (sq == sec) continue;                      // padding row -> zero
      const float4* src = (const float4*)(node_emb + (size_t)(off + sq) * HD + cg * 16);
      float4 v;
      v = src[0]; s0.x += v.x; s0.y += v.y; s0.z += v.z; s0.w += v.w;
      v = src[1]; s1.x += v.x; s1.y += v.y; s1.z += v.z; s1.w += v.w;
      v = src[2]; s2.x += v.x; s2.y += v.y; s2.z += v.z; s2.w += v.w;
      v = src[3]; s3.x += v.x; s3.y += v.y; s3.z += v.z; s3.w += v.w;
    }
    float v[16];
    v[0]=s0.x; v[1]=s0.y; v[2]=s0.z; v[3]=s0.w;
    v[4]=s1.x; v[5]=s1.y; v[6]=s1.z; v[7]=s1.w;
    v[8]=s2.x; v[9]=s2.y; v[10]=s2.z; v[11]=s2.w;
    v[12]=s3.x; v[13]=s3.y; v[14]=s3.z; v[15]=s3.w;
#pragma unroll
    for (int j = 0; j < 16; ++j)
      vn_bf[swz(r, cg * 16 + j)] = f2bf(v[j] * inv);
  }
  stage_fence();

  // ---- 3 SAN blocks ----
  const ushort* cur = vn_bf;
#pragma unroll 1
  for (int sb = 0; sb < 3; ++sb) {
    gemm_stage<false, false, false>(cur, Wv_bf, in_proj_b + 2 * HD, nullptr, bufA);  // t1 = x@Wv^T+bv
    stage_fence();
    gemm_stage<false, false, true>(bufA, Po_bf, out_proj_b, accf, bufB);             // attn (kept fp32)
    stage_fence();
    gemm_stage<true, false, false>(bufB, d1_bf, d1_b, nullptr, bufA);                // t2 = relu(attn@d1^T+b1)
    stage_fence();
    gemm_stage<false, true, false>(bufA, d2_bf, d2_b, accf, bufB);                   // x = attn + t2@d2^T+b2
    stage_fence();
    cur = bufB;
  }

  // ---- s_h = [v_n, s_g] @ W3^T + b3 (K=512) ----
  {
    int lane = t & 63, wid = t >> 6;
    int la = lane & 15, g = lane >> 4;
    int colb = wid * 64;
    f32x4 acc[4] = {{0.f,0.f,0.f,0.f},{0.f,0.f,0.f,0.f},{0.f,0.f,0.f,0.f},{0.f,0.f,0.f,0.f}};
#pragma unroll
    for (int kk = 0; kk < 16; ++kk) {
      const ushort* src = (kk < 8) ? vn_bf : cur;
      short8 a = *(const short8*)&src[swz(la, (kk & 7) * 32 + g * 8)];
#pragma unroll
      for (int ct = 0; ct < 4; ++ct) {
        int col = colb + ct * 16 + la;
        short8 b = *(const short8*)&W3_bf[col * 2 * HD + kk * 32 + g * 8];
        acc[ct] = __builtin_amdgcn_mfma_f32_16x16x32_bf16(a, b, acc[ct], 0, 0, 0);
      }
    }
#pragma unroll
    for (int ct = 0; ct < 4; ++ct) {
      int col = colb + ct * 16 + la;
      float bia = W3_b[col];
#pragma unroll
      for (int r = 0; r < 4; ++r) {
        int ro = g * 4 + r;
        float v = acc[ct][r] + bia;
        accf[ro * HD + col] = v;
        sh_bf[(size_t)(b0 + ro) * HD + col] = f2bf(v);
      }
    }
  }
  stage_fence();

  // ---- y_hat = dot(s_h, emb[cue]) in fp32 ----
  {
    int r = t >> 4, cg = t & 15;
    const float* er = emb_w + (size_t)cue[b0 + r] * HD + cg * 16;
    float p = 0.f;
#pragma unroll
    for (int j = 0; j < 16; ++j) p += accf[r * HD + cg * 16 + j] * er[j];
    red[r][cg] = p;
    __syncthreads();
    if (cg == 0) {
      float s = 0.f;
#pragma unroll
      for (int k = 0; k < 16; ++k) s += red[r][k];
      y_hat[b0 + r] = s;
    }
  }
}

// ---------------- all_scores = s_h @ emb^T  (block owns 64 vocab rows) ---
__global__ __launch_bounds__(256) void score_kernel(
    const ushort* __restrict__ sh_bf, const float* __restrict__ emb_w,
    float* __restrict__ scores, int nrows, int V) {
  __shared__ ushort ebuf[64 * HD];
  int t = threadIdx.x;
  int c0 = blockIdx.x * 64;
  // stage emb rows c0..c0+63 as bf16, XOR-swizzled
#pragma unroll
  for (int i = 0; i < 8; ++i) {
    int c = t + i * 256;           // chunk id, 64 rows * 32 chunks
    int row = c >> 5, q = c & 31;
    if (c0 + row < V) {
      const float4* src = (const float4*)(emb_w + (size_t)(c0 + row) * HD + q * 8);
      float4 v0 = src[0], v1 = src[1];
      short8 u;
      u[0] = (short)f2bf(v0.x); u[1] = (short)f2bf(v0.y);
      u[2] = (short)f2bf(v0.z); u[3] = (short)f2bf(v0.w);
      u[4] = (short)f2bf(v1.x); u[5] = (short)f2bf(v1.y);
      u[6] = (short)f2bf(v1.z); u[7] = (short)f2bf(v1.w);
      *(short8*)&ebuf[row * 256 + ((q ^ (row & 7)) * 8)] = u;
    }
  }
  __syncthreads();

  int lane = t & 63, wid = t >> 6;
  int la = lane & 15, g = lane >> 4;
  int nrb = nrows >> 6;
  for (int rb = 0; rb < nrb; ++rb) {
    int r0 = rb * 64 + wid * 16;
    const ushort* arow = sh_bf + (size_t)(r0 + la) * HD;
    short8 a[8];
#pragma unroll
    for (int kk = 0; kk < 8; ++kk) a[kk] = *(const short8*)&arow[kk * 32 + g * 8];
    f32x4 acc[4] = {{0.f,0.f,0.f,0.f},{0.f,0.f,0.f,0.f},{0.f,0.f,0.f,0.f},{0.f,0.f,0.f,0.f}};
#pragma unroll
    for (int kk = 0; kk < 8; ++kk) {
#pragma unroll
      for (int ct = 0; ct < 4; ++ct) {
        int brow = ct * 16 + la;
        short8 b = *(const short8*)&ebuf[brow * 256 + (((kk * 4 + g) ^ (brow & 7)) * 8)];
        acc[ct] = __builtin_amdgcn_mfma_f32_16x16x32_bf16(a[kk], b, acc[ct], 0, 0, 0);
      }
    }
#pragma unroll
    for (int ct = 0; ct < 4; ++ct) {
      int col = c0 + ct * 16 + la;
      if (col < V) {
#pragma unroll
        for (int r = 0; r < 4; ++r) {
          int m = r0 + g * 4 + r;
          scores[(size_t)m * V + col] = acc[ct][r];
        }
      }
    }
  }
}

extern "C" void kernel_launch(void* const* d_in, const int* in_sizes, int n_in,
                              void* d_out, int out_size, void* d_ws, size_t ws_size,
                              hipStream_t stream) {
  const float* node_emb   = (const float*)d_in[0];
  const float* emb_w      = (const float*)d_in[1];
  const float* itemset_len= (const float*)d_in[2];
  const float* in_proj_w  = (const float*)d_in[3];
  const float* in_proj_b  = (const float*)d_in[4];
  const float* out_proj_w = (const float*)d_in[5];
  const float* out_proj_b = (const float*)d_in[6];
  const float* d1_w       = (const float*)d_in[7];
  const float* d1_b       = (const float*)d_in[8];
  const float* d2_w       = (const float*)d_in[9];
  const float* d2_b       = (const float*)d_in[10];
  const float* W3_w       = (const float*)d_in[11];
  const float* W3_b       = (const float*)d_in[12];
  const int*   batch      = (const int*)d_in[13];
  const int*   sequence   = (const int*)d_in[14];
  const int*   seq_len    = (const int*)d_in[15];
  const int*   cue        = (const int*)d_in[16];

  int total_nodes = in_sizes[0] / HD;
  int V           = in_sizes[1] / HD;
  int nsess       = in_sizes[15];
  int total_steps = in_sizes[2];
  int group       = in_sizes[14] / total_steps;

  char* ws = (char*)d_ws;
  int* sections   = (int*)(ws);
  int* offsets    = (int*)(ws + 4096);
  int* last_idx   = (int*)(ws + 8192);
  ushort* sh_bf   = (ushort*)(ws + 16384);                 // nsess*256 bf16
  ushort* Wv_bf   = (ushort*)(ws + 16384 + 524288);
  ushort* Po_bf   = Wv_bf + HD * HD;
  ushort* d1_bf   = Po_bf + HD * HD;
  ushort* d2_bf   = d1_bf + HD * HD;
  ushort* W3_bf   = d2_bf + HD * HD;

  float* y_hat  = (float*)d_out;
  float* scores = (float*)d_out + nsess;

  hipMemsetAsync(sections, 0, (size_t)nsess * sizeof(int), stream);
  prep1_kernel<<<512, 256, 0, stream>>>(batch, total_nodes, sections,
                                        in_proj_w, out_proj_w, d1_w, d2_w, W3_w,
                                        Wv_bf, Po_bf, d1_bf, d2_bf, W3_bf);
  scan_kernel<<<1, 1024, 0, stream>>>(seq_len, sections, offsets, last_idx, nsess);
  sh_kernel<<<nsess / 16, 256, 0, stream>>>(node_emb, emb_w, itemset_len, in_proj_b,
                                            out_proj_b, d1_b, d2_b, W3_b,
                                            sequence, cue, sections, offsets, last_idx,
                                            Wv_bf, Po_bf, d1_bf, d2_bf, W3_bf,
                                            sh_bf, y_hat, group);
  score_kernel<<<(V + 63) / 64, 256, 0, stream>>>(sh_bf, emb_w, scores, nsess, V);
}

// Round 3
// 162.754 us; speedup vs baseline: 1.0130x; 1.0130x over previous
//
#include <hip/hip_runtime.h>
#include <hip/hip_bf16.h>
#include <stdint.h>

typedef __attribute__((ext_vector_type(8))) short short8;
typedef __attribute__((ext_vector_type(4))) short short4v;
typedef __attribute__((ext_vector_type(4))) float f32x4;

#define HD 256

__device__ __forceinline__ ushort f2bf(float f) {
  union { float f; uint32_t u; } x; x.f = f;
  uint32_t r = (x.u + 0x7fffu + ((x.u >> 16) & 1u)) >> 16;
  return (ushort)r;
}

// swizzled index (ushort units) into a [rows][256] bf16 LDS buffer.
// XOR-swizzle per 16B chunk to kill the row-stride-512B bank conflict (G4).
__device__ __forceinline__ int swz(int row, int col) {
  int chunk = (col >> 3) ^ (row & 7);
  return row * 256 + chunk * 8 + (col & 7);
}

// ---------------- prep: bincount + weight bf16 conversion ----------------
__global__ void prep1_kernel(const int* __restrict__ batch, int total_nodes,
                             int* __restrict__ sections,
                             const float* __restrict__ in_proj_w,
                             const float* __restrict__ out_proj_w,
                             const float* __restrict__ d1_w,
                             const float* __restrict__ d2_w,
                             const float* __restrict__ W3_w,
                             ushort* __restrict__ Wv_bf, ushort* __restrict__ Po_bf,
                             ushort* __restrict__ d1_bf, ushort* __restrict__ d2_bf,
                             ushort* __restrict__ W3_bf) {
  int stride = gridDim.x * blockDim.x;
  int t0 = blockIdx.x * blockDim.x + threadIdx.x;
  for (int i = t0; i < total_nodes; i += stride)
    atomicAdd(&sections[batch[i]], 1);
  for (int i = t0; i < HD * HD; i += stride) {
    Wv_bf[i] = f2bf(in_proj_w[2 * HD * HD + i]);
    Po_bf[i] = f2bf(out_proj_w[i]);
    d1_bf[i] = f2bf(d1_w[i]);
    d2_bf[i] = f2bf(d2_w[i]);
  }
  for (int i = t0; i < HD * 2 * HD; i += stride)
    W3_bf[i] = f2bf(W3_w[i]);
}

// ---------------- scan: offsets (exclusive) + last_idx (inclusive-1) -----
__global__ void scan_kernel(const int* __restrict__ seq_len, int* __restrict__ sections,
                            int* __restrict__ offsets, int* __restrict__ last_idx,
                            int nsess) {
  __shared__ int s1[1024];
  __shared__ int s2[1024];
  int t = threadIdx.x;
  int v1 = (t < nsess) ? sections[t] : 0;
  int v2 = (t < nsess) ? seq_len[t] : 0;
  s1[t] = v1; s2[t] = v2;
  for (int d = 1; d < 1024; d <<= 1) {
    __syncthreads();
    int a1 = (t >= d) ? s1[t - d] : 0;
    int a2 = (t >= d) ? s2[t - d] : 0;
    __syncthreads();
    s1[t] += a1; s2[t] += a2;
  }
  __syncthreads();
  if (t < nsess) {
    offsets[t] = s1[t] - v1;     // exclusive cumsum of sections
    last_idx[t] = s2[t] - 1;     // cumsum(sequence_len) - 1
  }
}

// ---- one SAN GEMM stage, 16-wave version: each wave owns a 16x16 tile ----
// Per-thread weight loads = 8 x 16B = 32 VGPR, so even if LICM hoists all
// four in-loop stages (the round-1/2 spill bug: 4 x 128 VGPR > 256 -> 9.3MB
// scratch traffic) the worst case is 128 VGPR — provably spill-free.
template<bool RELU, bool RESID, bool WACC>
__device__ __forceinline__ void gemm_stage16(const ushort* inA, const ushort* __restrict__ Wbf,
                                             const float* __restrict__ bias,
                                             float* accf, ushort* outB) {
  int t = threadIdx.x;
  int lane = t & 63, wid = t >> 6;       // 16 waves
  int la = lane & 15, g = lane >> 4;
  int col = wid * 16 + la;
  f32x4 acc = {0.f, 0.f, 0.f, 0.f};
#pragma unroll
  for (int kk = 0; kk < 8; ++kk) {
    short8 a = *(const short8*)&inA[swz(la, kk * 32 + g * 8)];
    short8 b = *(const short8*)&Wbf[col * HD + kk * 32 + g * 8];
    acc = __builtin_amdgcn_mfma_f32_16x16x32_bf16(a, b, acc, 0, 0, 0);
  }
  float bia = bias[col];
#pragma unroll
  for (int r = 0; r < 4; ++r) {
    int ro = g * 4 + r;
    float v = acc[r] + bia;
    if (RELU) v = fmaxf(v, 0.f);
    if (RESID) v += accf[ro * HD + col];
    if (WACC) accf[ro * HD + col] = v;
    outB[swz(ro, col)] = f2bf(v);
  }
}

__device__ __forceinline__ void stage_fence() {
  __syncthreads();
  __builtin_amdgcn_sched_barrier(0);
}

// -------- v_n + SAN x3 + s_h + y_hat (16 rows / block, 16 waves) ---------
__global__ __launch_bounds__(1024, 1) void sh_kernel(
    const float* __restrict__ node_emb, const float* __restrict__ emb_w,
    const float* __restrict__ itemset_len, const float* __restrict__ in_proj_b,
    const float* __restrict__ out_proj_b, const float* __restrict__ d1_b,
    const float* __restrict__ d2_b, const float* __restrict__ W3_b,
    const int* __restrict__ sequence, const int* __restrict__ cue,
    const int* __restrict__ sections, const int* __restrict__ offsets,
    const int* __restrict__ last_idx,
    const ushort* __restrict__ Wv_bf, const ushort* __restrict__ Po_bf,
    const ushort* __restrict__ d1_bf, const ushort* __restrict__ d2_bf,
    const ushort* __restrict__ W3_bf,
    ushort* __restrict__ sh_bf, float* __restrict__ y_hat, int group) {
  __shared__ float accf[16 * HD];
  __shared__ ushort vn_bf[16 * HD];
  __shared__ ushort bufA[16 * HD];
  __shared__ ushort bufB[16 * HD];
  int t = threadIdx.x;
  int b0 = blockIdx.x * 16;

  // ---- v_n: gather last-step itemset embedding (1 float4 per thread) ----
  {
    int r = t >> 6, cg = t & 63;         // row r, 64 threads/row, 4 floats each
    int sess = b0 + r;
    int li = last_idx[sess];
    float inv = 1.0f / itemset_len[li];
    int sec = sections[sess], off = offsets[sess];
    float4 s = {0.f, 0.f, 0.f, 0.f};
    for (int gi = 0; gi < group; ++gi) {
      int sq = sequence[li * group + gi];
      if (sq == sec) continue;           // padding row -> zero
      float4 v = *(const float4*)(node_emb + (size_t)(off + sq) * HD + cg * 4);
      s.x += v.x; s.y += v.y; s.z += v.z; s.w += v.w;
    }
    short4v u;
    u[0] = (short)f2bf(s.x * inv); u[1] = (short)f2bf(s.y * inv);
    u[2] = (short)f2bf(s.z * inv); u[3] = (short)f2bf(s.w * inv);
    *(short4v*)&vn_bf[swz(r, cg * 4)] = u;   // cg*4 % 8 in {0,4}: stays in chunk
  }
  stage_fence();

  // ---- 3 SAN blocks ----
  const ushort* cur = vn_bf;
#pragma unroll 1
  for (int sb = 0; sb < 3; ++sb) {
    gemm_stage16<false, false, false>(cur, Wv_bf, in_proj_b + 2 * HD, nullptr, bufA); // t1 = x@Wv^T+bv
    stage_fence();
    gemm_stage16<false, false, true>(bufA, Po_bf, out_proj_b, accf, bufB);            // attn (fp32 in accf)
    stage_fence();
    gemm_stage16<true, false, false>(bufB, d1_bf, d1_b, nullptr, bufA);               // t2 = relu(attn@d1^T+b1)
    stage_fence();
    gemm_stage16<false, true, false>(bufA, d2_bf, d2_b, accf, bufB);                  // x = attn + t2@d2^T+b2
    stage_fence();
    cur = bufB;
  }

  // ---- s_h = [v_n, s_g] @ W3^T + b3 (K=512), 1 col-tile per wave ----
  {
    int lane = t & 63, wid = t >> 6;
    int la = lane & 15, g = lane >> 4;
    int col = wid * 16 + la;
    f32x4 acc = {0.f, 0.f, 0.f, 0.f};
#pragma unroll
    for (int kk = 0; kk < 16; ++kk) {
      const ushort* src = (kk < 8) ? vn_bf : cur;
      short8 a = *(const short8*)&src[swz(la, (kk & 7) * 32 + g * 8)];
      short8 b = *(const short8*)&W3_bf[col * 2 * HD + kk * 32 + g * 8];
      acc = __builtin_amdgcn_mfma_f32_16x16x32_bf16(a, b, acc, 0, 0, 0);
    }
    float bia = W3_b[col];
#pragma unroll
    for (int r = 0; r < 4; ++r) {
      int ro = g * 4 + r;
      float v = acc[r] + bia;
      accf[ro * HD + col] = v;
      sh_bf[(size_t)(b0 + ro) * HD + col] = f2bf(v);
    }
  }
  stage_fence();

  // ---- y_hat = dot(s_h, emb[cue]) in fp32; one wave per row ----
  {
    int r = t >> 6, lane = t & 63;
    const float4 er = *(const float4*)(emb_w + (size_t)cue[b0 + r] * HD + lane * 4);
    const float* ar = &accf[r * HD + lane * 4];
    float p = ar[0] * er.x + ar[1] * er.y + ar[2] * er.z + ar[3] * er.w;
#pragma unroll
    for (int off = 32; off >= 1; off >>= 1) p += __shfl_down(p, off, 64);
    if (lane == 0) y_hat[b0 + r] = p;
  }
}

// ---------------- all_scores = s_h @ emb^T  (block owns 64 vocab rows) ---
__global__ __launch_bounds__(256) void score_kernel(
    const ushort* __restrict__ sh_bf, const float* __restrict__ emb_w,
    float* __restrict__ scores, int nrows, int V) {
  __shared__ ushort ebuf[64 * HD];
  int t = threadIdx.x;
  int c0 = blockIdx.x * 64;
  // stage emb rows c0..c0+63 as bf16, XOR-swizzled
#pragma unroll
  for (int i = 0; i < 8; ++i) {
    int c = t + i * 256;           // chunk id, 64 rows * 32 chunks
    int row = c >> 5, q = c & 31;
    if (c0 + row < V) {
      const float4* src = (const float4*)(emb_w + (size_t)(c0 + row) * HD + q * 8);
      float4 v0 = src[0], v1 = src[1];
      short8 u;
      u[0] = (short)f2bf(v0.x); u[1] = (short)f2bf(v0.y);
      u[2] = (short)f2bf(v0.z); u[3] = (short)f2bf(v0.w);
      u[4] = (short)f2bf(v1.x); u[5] = (short)f2bf(v1.y);
      u[6] = (short)f2bf(v1.z); u[7] = (short)f2bf(v1.w);
      *(short8*)&ebuf[row * 256 + ((q ^ (row & 7)) * 8)] = u;
    }
  }
  __syncthreads();

  int lane = t & 63, wid = t >> 6;
  int la = lane & 15, g = lane >> 4;
  int nrb = nrows >> 6;
  for (int rb = 0; rb < nrb; ++rb) {
    int r0 = rb * 64 + wid * 16;
    const ushort* arow = sh_bf + (size_t)(r0 + la) * HD;
    short8 a[8];
#pragma unroll
    for (int kk = 0; kk < 8; ++kk) a[kk] = *(const short8*)&arow[kk * 32 + g * 8];
    f32x4 acc[4] = {{0.f,0.f,0.f,0.f},{0.f,0.f,0.f,0.f},{0.f,0.f,0.f,0.f},{0.f,0.f,0.f,0.f}};
#pragma unroll
    for (int kk = 0; kk < 8; ++kk) {
#pragma unroll
      for (int ct = 0; ct < 4; ++ct) {
        int brow = ct * 16 + la;
        short8 b = *(const short8*)&ebuf[brow * 256 + (((kk * 4 + g) ^ (brow & 7)) * 8)];
        acc[ct] = __builtin_amdgcn_mfma_f32_16x16x32_bf16(a[kk], b, acc[ct], 0, 0, 0);
      }
    }
#pragma unroll
    for (int ct = 0; ct < 4; ++ct) {
      int col = c0 + ct * 16 + la;
      if (col < V) {
#pragma unroll
        for (int r = 0; r < 4; ++r) {
          int m = r0 + g * 4 + r;
          scores[(size_t)m * V + col] = acc[ct][r];
        }
      }
    }
  }
}

extern "C" void kernel_launch(void* const* d_in, const int* in_sizes, int n_in,
                              void* d_out, int out_size, void* d_ws, size_t ws_size,
                              hipStream_t stream) {
  const float* node_emb   = (const float*)d_in[0];
  const float* emb_w      = (const float*)d_in[1];
  const float* itemset_len= (const float*)d_in[2];
  const float* in_proj_w  = (const float*)d_in[3];
  const float* in_proj_b  = (const float*)d_in[4];
  const float* out_proj_w = (const float*)d_in[5];
  const float* out_proj_b = (const float*)d_in[6];
  const float* d1_w       = (const float*)d_in[7];
  const float* d1_b       = (const float*)d_in[8];
  const float* d2_w       = (const float*)d_in[9];
  const float* d2_b       = (const float*)d_in[10];
  const float* W3_w       = (const float*)d_in[11];
  const float* W3_b       = (const float*)d_in[12];
  const int*   batch      = (const int*)d_in[13];
  const int*   sequence   = (const int*)d_in[14];
  const int*   seq_len    = (const int*)d_in[15];
  const int*   cue        = (const int*)d_in[16];

  int total_nodes = in_sizes[0] / HD;
  int V           = in_sizes[1] / HD;
  int nsess       = in_sizes[15];
  int total_steps = in_sizes[2];
  int group       = in_sizes[14] / total_steps;

  char* ws = (char*)d_ws;
  int* sections   = (int*)(ws);
  int* offsets    = (int*)(ws + 4096);
  int* last_idx   = (int*)(ws + 8192);
  ushort* sh_bf   = (ushort*)(ws + 16384);                 // nsess*256 bf16
  ushort* Wv_bf   = (ushort*)(ws + 16384 + 524288);
  ushort* Po_bf   = Wv_bf + HD * HD;
  ushort* d1_bf   = Po_bf + HD * HD;
  ushort* d2_bf   = d1_bf + HD * HD;
  ushort* W3_bf   = d2_bf + HD * HD;

  float* y_hat  = (float*)d_out;
  float* scores = (float*)d_out + nsess;

  hipMemsetAsync(sections, 0, (size_t)nsess * sizeof(int), stream);
  prep1_kernel<<<512, 256, 0, stream>>>(batch, total_nodes, sections,
                                        in_proj_w, out_proj_w, d1_w, d2_w, W3_w,
                                        Wv_bf, Po_bf, d1_bf, d2_bf, W3_bf);
  scan_kernel<<<1, 1024, 0, stream>>>(seq_len, sections, offsets, last_idx, nsess);
  sh_kernel<<<nsess / 16, 1024, 0, stream>>>(node_emb, emb_w, itemset_len, in_proj_b,
                                             out_proj_b, d1_b, d2_b, W3_b,
                                             sequence, cue, sections, offsets, last_idx,
                                             Wv_bf, Po_bf, d1_bf, d2_bf, W3_bf,
                                             sh_bf, y_hat, group);
  score_kernel<<<(V + 63) / 64, 256, 0, stream>>>(sh_bf, emb_w, scores, nsess, V);
}

// Round 4
// 162.449 us; speedup vs baseline: 1.0149x; 1.0019x over previous
//
#include <hip/hip_runtime.h>
#include <hip/hip_bf16.h>
#include <stdint.h>

typedef __attribute__((ext_vector_type(8))) short short8;
typedef __attribute__((ext_vector_type(4))) short short4v;
typedef __attribute__((ext_vector_type(4))) float f32x4;

#define HD 256

__device__ __forceinline__ ushort f2bf(float f) {
  union { float f; uint32_t u; } x; x.f = f;
  uint32_t r = (x.u + 0x7fffu + ((x.u >> 16) & 1u)) >> 16;
  return (ushort)r;
}

// swizzled index (ushort units) into a [rows][256] bf16 LDS buffer.
// XOR-swizzle per 16B chunk to kill the row-stride-512B bank conflict (G4).
__device__ __forceinline__ int swz(int row, int col) {
  int chunk = (col >> 3) ^ (row & 7);
  return row * 256 + chunk * 8 + (col & 7);
}

// ---- zero sections WITHOUT hipMemsetAsync: an in-graph memset node becomes
// a rocclr fillBufferAligned replayed every iteration at ~115us regardless of
// size (round-2/3 profiles: 4KB-write fills with the same dur/VALUBusy/Occ
// fingerprint as 800MB fills). A plain 1-block kernel is ~2us.
__global__ void zero_kernel(int* __restrict__ p, int n) {
  for (int i = threadIdx.x; i < n; i += blockDim.x) p[i] = 0;
}

// ---------------- prep: bincount + weight bf16 conversion ----------------
__global__ void prep1_kernel(const int* __restrict__ batch, int total_nodes,
                             int* __restrict__ sections,
                             const float* __restrict__ in_proj_w,
                             const float* __restrict__ out_proj_w,
                             const float* __restrict__ d1_w,
                             const float* __restrict__ d2_w,
                             const float* __restrict__ W3_w,
                             ushort* __restrict__ Wv_bf, ushort* __restrict__ Po_bf,
                             ushort* __restrict__ d1_bf, ushort* __restrict__ d2_bf,
                             ushort* __restrict__ W3_bf) {
  int stride = gridDim.x * blockDim.x;
  int t0 = blockIdx.x * blockDim.x + threadIdx.x;
  for (int i = t0; i < total_nodes; i += stride)
    atomicAdd(&sections[batch[i]], 1);
  for (int i = t0; i < HD * HD; i += stride) {
    Wv_bf[i] = f2bf(in_proj_w[2 * HD * HD + i]);
    Po_bf[i] = f2bf(out_proj_w[i]);
    d1_bf[i] = f2bf(d1_w[i]);
    d2_bf[i] = f2bf(d2_w[i]);
  }
  for (int i = t0; i < HD * 2 * HD; i += stride)
    W3_bf[i] = f2bf(W3_w[i]);
}

// ---------------- scan: offsets (exclusive) + last_idx (inclusive-1) -----
__global__ void scan_kernel(const int* __restrict__ seq_len, int* __restrict__ sections,
                            int* __restrict__ offsets, int* __restrict__ last_idx,
                            int nsess) {
  __shared__ int s1[1024];
  __shared__ int s2[1024];
  int t = threadIdx.x;
  int v1 = (t < nsess) ? sections[t] : 0;
  int v2 = (t < nsess) ? seq_len[t] : 0;
  s1[t] = v1; s2[t] = v2;
  for (int d = 1; d < 1024; d <<= 1) {
    __syncthreads();
    int a1 = (t >= d) ? s1[t - d] : 0;
    int a2 = (t >= d) ? s2[t - d] : 0;
    __syncthreads();
    s1[t] += a1; s2[t] += a2;
  }
  __syncthreads();
  if (t < nsess) {
    offsets[t] = s1[t] - v1;     // exclusive cumsum of sections
    last_idx[t] = s2[t] - 1;     // cumsum(sequence_len) - 1
  }
}

// ---- one SAN GEMM stage, 16-wave version: each wave owns a 16x16 tile ----
// Per-thread weight loads = 8 x 16B = 32 VGPR, so even if LICM hoists all
// four in-loop stages the worst case is 128 VGPR — provably spill-free.
template<bool RELU, bool RESID, bool WACC>
__device__ __forceinline__ void gemm_stage16(const ushort* inA, const ushort* __restrict__ Wbf,
                                             const float* __restrict__ bias,
                                             float* accf, ushort* outB) {
  int t = threadIdx.x;
  int lane = t & 63, wid = t >> 6;       // 16 waves
  int la = lane & 15, g = lane >> 4;
  int col = wid * 16 + la;
  f32x4 acc = {0.f, 0.f, 0.f, 0.f};
#pragma unroll
  for (int kk = 0; kk < 8; ++kk) {
    short8 a = *(const short8*)&inA[swz(la, kk * 32 + g * 8)];
    short8 b = *(const short8*)&Wbf[col * HD + kk * 32 + g * 8];
    acc = __builtin_amdgcn_mfma_f32_16x16x32_bf16(a, b, acc, 0, 0, 0);
  }
  float bia = bias[col];
#pragma unroll
  for (int r = 0; r < 4; ++r) {
    int ro = g * 4 + r;
    float v = acc[r] + bia;
    if (RELU) v = fmaxf(v, 0.f);
    if (RESID) v += accf[ro * HD + col];
    if (WACC) accf[ro * HD + col] = v;
    outB[swz(ro, col)] = f2bf(v);
  }
}

__device__ __forceinline__ void stage_fence() {
  __syncthreads();
  __builtin_amdgcn_sched_barrier(0);
}

// -------- v_n + SAN x3 + s_h + y_hat (16 rows / block, 16 waves) ---------
__global__ __launch_bounds__(1024, 1) void sh_kernel(
    const float* __restrict__ node_emb, const float* __restrict__ emb_w,
    const float* __restrict__ itemset_len, const float* __restrict__ in_proj_b,
    const float* __restrict__ out_proj_b, const float* __restrict__ d1_b,
    const float* __restrict__ d2_b, const float* __restrict__ W3_b,
    const int* __restrict__ sequence, const int* __restrict__ cue,
    const int* __restrict__ sections, const int* __restrict__ offsets,
    const int* __restrict__ last_idx,
    const ushort* __restrict__ Wv_bf, const ushort* __restrict__ Po_bf,
    const ushort* __restrict__ d1_bf, const ushort* __restrict__ d2_bf,
    const ushort* __restrict__ W3_bf,
    ushort* __restrict__ sh_bf, float* __restrict__ y_hat, int group) {
  __shared__ float accf[16 * HD];
  __shared__ ushort vn_bf[16 * HD];
  __shared__ ushort bufA[16 * HD];
  __shared__ ushort bufB[16 * HD];
  int t = threadIdx.x;
  int b0 = blockIdx.x * 16;

  // ---- v_n: gather last-step itemset embedding (1 float4 per thread) ----
  {
    int r = t >> 6, cg = t & 63;         // row r, 64 threads/row, 4 floats each
    int sess = b0 + r;
    int li = last_idx[sess];
    float inv = 1.0f / itemset_len[li];
    int sec = sections[sess], off = offsets[sess];
    float4 s = {0.f, 0.f, 0.f, 0.f};
    for (int gi = 0; gi < group; ++gi) {
      int sq = sequence[li * group + gi];
      if (sq == sec) continue;           // padding row -> zero
      float4 v = *(const float4*)(node_emb + (size_t)(off + sq) * HD + cg * 4);
      s.x += v.x; s.y += v.y; s.z += v.z; s.w += v.w;
    }
    short4v u;
    u[0] = (short)f2bf(s.x * inv); u[1] = (short)f2bf(s.y * inv);
    u[2] = (short)f2bf(s.z * inv); u[3] = (short)f2bf(s.w * inv);
    *(short4v*)&vn_bf[swz(r, cg * 4)] = u;   // cg*4 % 8 in {0,4}: stays in chunk
  }
  stage_fence();

  // ---- 3 SAN blocks ----
  const ushort* cur = vn_bf;
#pragma unroll 1
  for (int sb = 0; sb < 3; ++sb) {
    gemm_stage16<false, false, false>(cur, Wv_bf, in_proj_b + 2 * HD, nullptr, bufA); // t1 = x@Wv^T+bv
    stage_fence();
    gemm_stage16<false, false, true>(bufA, Po_bf, out_proj_b, accf, bufB);            // attn (fp32 in accf)
    stage_fence();
    gemm_stage16<true, false, false>(bufB, d1_bf, d1_b, nullptr, bufA);               // t2 = relu(attn@d1^T+b1)
    stage_fence();
    gemm_stage16<false, true, false>(bufA, d2_bf, d2_b, accf, bufB);                  // x = attn + t2@d2^T+b2
    stage_fence();
    cur = bufB;
  }

  // ---- s_h = [v_n, s_g] @ W3^T + b3 (K=512), 1 col-tile per wave ----
  {
    int lane = t & 63, wid = t >> 6;
    int la = lane & 15, g = lane >> 4;
    int col = wid * 16 + la;
    f32x4 acc = {0.f, 0.f, 0.f, 0.f};
#pragma unroll
    for (int kk = 0; kk < 16; ++kk) {
      const ushort* src = (kk < 8) ? vn_bf : cur;
      short8 a = *(const short8*)&src[swz(la, (kk & 7) * 32 + g * 8)];
      short8 b = *(const short8*)&W3_bf[col * 2 * HD + kk * 32 + g * 8];
      acc = __builtin_amdgcn_mfma_f32_16x16x32_bf16(a, b, acc, 0, 0, 0);
    }
    float bia = W3_b[col];
#pragma unroll
    for (int r = 0; r < 4; ++r) {
      int ro = g * 4 + r;
      float v = acc[r] + bia;
      accf[ro * HD + col] = v;
      sh_bf[(size_t)(b0 + ro) * HD + col] = f2bf(v);
    }
  }
  stage_fence();

  // ---- y_hat = dot(s_h, emb[cue]) in fp32; one wave per row ----
  {
    int r = t >> 6, lane = t & 63;
    const float4 er = *(const float4*)(emb_w + (size_t)cue[b0 + r] * HD + lane * 4);
    const float* ar = &accf[r * HD + lane * 4];
    float p = ar[0] * er.x + ar[1] * er.y + ar[2] * er.z + ar[3] * er.w;
#pragma unroll
    for (int off = 32; off >= 1; off >>= 1) p += __shfl_down(p, off, 64);
    if (lane == 0) y_hat[b0 + r] = p;
  }
}

// ---------------- all_scores = s_h @ emb^T  (block owns 64 vocab rows) ---
__global__ __launch_bounds__(256) void score_kernel(
    const ushort* __restrict__ sh_bf, const float* __restrict__ emb_w,
    float* __restrict__ scores, int nrows, int V) {
  __shared__ ushort ebuf[64 * HD];
  int t = threadIdx.x;
  int c0 = blockIdx.x * 64;
  // stage emb rows c0..c0+63 as bf16, XOR-swizzled
#pragma unroll
  for (int i = 0; i < 8; ++i) {
    int c = t + i * 256;           // chunk id, 64 rows * 32 chunks
    int row = c >> 5, q = c & 31;
    if (c0 + row < V) {
      const float4* src = (const float4*)(emb_w + (size_t)(c0 + row) * HD + q * 8);
      float4 v0 = src[0], v1 = src[1];
      short8 u;
      u[0] = (short)f2bf(v0.x); u[1] = (short)f2bf(v0.y);
      u[2] = (short)f2bf(v0.z); u[3] = (short)f2bf(v0.w);
      u[4] = (short)f2bf(v1.x); u[5] = (short)f2bf(v1.y);
      u[6] = (short)f2bf(v1.z); u[7] = (short)f2bf(v1.w);
      *(short8*)&ebuf[row * 256 + ((q ^ (row & 7)) * 8)] = u;
    }
  }
  __syncthreads();

  int lane = t & 63, wid = t >> 6;
  int la = lane & 15, g = lane >> 4;
  int nrb = nrows >> 6;
  for (int rb = 0; rb < nrb; ++rb) {
    int r0 = rb * 64 + wid * 16;
    const ushort* arow = sh_bf + (size_t)(r0 + la) * HD;
    short8 a[8];
#pragma unroll
    for (int kk = 0; kk < 8; ++kk) a[kk] = *(const short8*)&arow[kk * 32 + g * 8];
    f32x4 acc[4] = {{0.f,0.f,0.f,0.f},{0.f,0.f,0.f,0.f},{0.f,0.f,0.f,0.f},{0.f,0.f,0.f,0.f}};
#pragma unroll
    for (int kk = 0; kk < 8; ++kk) {
#pragma unroll
      for (int ct = 0; ct < 4; ++ct) {
        int brow = ct * 16 + la;
        short8 b = *(const short8*)&ebuf[brow * 256 + (((kk * 4 + g) ^ (brow & 7)) * 8)];
        acc[ct] = __builtin_amdgcn_mfma_f32_16x16x32_bf16(a[kk], b, acc[ct], 0, 0, 0);
      }
    }
#pragma unroll
    for (int ct = 0; ct < 4; ++ct) {
      int col = c0 + ct * 16 + la;
      if (col < V) {
#pragma unroll
        for (int r = 0; r < 4; ++r) {
          int m = r0 + g * 4 + r;
          scores[(size_t)m * V + col] = acc[ct][r];
        }
      }
    }
  }
}

extern "C" void kernel_launch(void* const* d_in, const int* in_sizes, int n_in,
                              void* d_out, int out_size, void* d_ws, size_t ws_size,
                              hipStream_t stream) {
  const float* node_emb   = (const float*)d_in[0];
  const float* emb_w      = (const float*)d_in[1];
  const float* itemset_len= (const float*)d_in[2];
  const float* in_proj_w  = (const float*)d_in[3];
  const float* in_proj_b  = (const float*)d_in[4];
  const float* out_proj_w = (const float*)d_in[5];
  const float* out_proj_b = (const float*)d_in[6];
  const float* d1_w       = (const float*)d_in[7];
  const float* d1_b       = (const float*)d_in[8];
  const float* d2_w       = (const float*)d_in[9];
  const float* d2_b       = (const float*)d_in[10];
  const float* W3_w       = (const float*)d_in[11];
  const float* W3_b       = (const float*)d_in[12];
  const int*   batch      = (const int*)d_in[13];
  const int*   sequence   = (const int*)d_in[14];
  const int*   seq_len    = (const int*)d_in[15];
  const int*   cue        = (const int*)d_in[16];

  int total_nodes = in_sizes[0] / HD;
  int V           = in_sizes[1] / HD;
  int nsess       = in_sizes[15];
  int total_steps = in_sizes[2];
  int group       = in_sizes[14] / total_steps;

  char* ws = (char*)d_ws;
  int* sections   = (int*)(ws);
  int* offsets    = (int*)(ws + 4096);
  int* last_idx   = (int*)(ws + 8192);
  ushort* sh_bf   = (ushort*)(ws + 16384);                 // nsess*256 bf16
  ushort* Wv_bf   = (ushort*)(ws + 16384 + 524288);
  ushort* Po_bf   = Wv_bf + HD * HD;
  ushort* d1_bf   = Po_bf + HD * HD;
  ushort* d2_bf   = d1_bf + HD * HD;
  ushort* W3_bf   = d2_bf + HD * HD;

  float* y_hat  = (float*)d_out;
  float* scores = (float*)d_out + nsess;

  zero_kernel<<<1, 1024, 0, stream>>>(sections, nsess);
  prep1_kernel<<<512, 256, 0, stream>>>(batch, total_nodes, sections,
                                        in_proj_w, out_proj_w, d1_w, d2_w, W3_w,
                                        Wv_bf, Po_bf, d1_bf, d2_bf, W3_bf);
  scan_kernel<<<1, 1024, 0, stream>>>(seq_len, sections, offsets, last_idx, nsess);
  sh_kernel<<<nsess / 16, 1024, 0, stream>>>(node_emb, emb_w, itemset_len, in_proj_b,
                                             out_proj_b, d1_b, d2_b, W3_b,
                                             sequence, cue, sections, offsets, last_idx,
                                             Wv_bf, Po_bf, d1_bf, d2_bf, W3_bf,
                                             sh_bf, y_hat, group);
  score_kernel<<<(V + 63) / 64, 256, 0, stream>>>(sh_bf, emb_w, scores, nsess, V);
}

// Round 5
// 154.199 us; speedup vs baseline: 1.0692x; 1.0535x over previous
//
#include <hip/hip_runtime.h>
#include <hip/hip_bf16.h>
#include <stdint.h>

typedef __attribute__((ext_vector_type(8))) short short8;
typedef __attribute__((ext_vector_type(4))) short short4v;
typedef __attribute__((ext_vector_type(4))) float f32x4;

#define HD 256

__device__ __forceinline__ ushort f2bf(float f) {
  union { float f; uint32_t u; } x; x.f = f;
  uint32_t r = (x.u + 0x7fffu + ((x.u >> 16) & 1u)) >> 16;
  return (ushort)r;
}

// swizzled index (ushort units) into a [rows][256] bf16 LDS buffer.
// XOR-swizzle per 16B chunk to kill the row-stride-512B bank conflict (G4).
__device__ __forceinline__ int swz(int row, int col) {
  int chunk = (col >> 3) ^ (row & 7);
  return row * 256 + chunk * 8 + (col & 7);
}

__global__ void zero_kernel(int* __restrict__ p, int n) {
  for (int i = threadIdx.x; i < n; i += blockDim.x) p[i] = 0;
}

// ---------------- prep: bincount + weight bf16 conversion ----------------
__global__ void prep1_kernel(const int* __restrict__ batch, int total_nodes,
                             int* __restrict__ sections,
                             const float* __restrict__ in_proj_w,
                             const float* __restrict__ out_proj_w,
                             const float* __restrict__ d1_w,
                             const float* __restrict__ d2_w,
                             const float* __restrict__ W3_w,
                             ushort* __restrict__ Wv_bf, ushort* __restrict__ Po_bf,
                             ushort* __restrict__ d1_bf, ushort* __restrict__ d2_bf,
                             ushort* __restrict__ W3_bf) {
  int stride = gridDim.x * blockDim.x;
  int t0 = blockIdx.x * blockDim.x + threadIdx.x;
  for (int i = t0; i < total_nodes; i += stride)
    atomicAdd(&sections[batch[i]], 1);
  for (int i = t0; i < HD * HD; i += stride) {
    Wv_bf[i] = f2bf(in_proj_w[2 * HD * HD + i]);
    Po_bf[i] = f2bf(out_proj_w[i]);
    d1_bf[i] = f2bf(d1_w[i]);
    d2_bf[i] = f2bf(d2_w[i]);
  }
  for (int i = t0; i < HD * 2 * HD; i += stride)
    W3_bf[i] = f2bf(W3_w[i]);
}

// ---------------- scan: offsets (exclusive) + last_idx (inclusive-1) -----
__global__ void scan_kernel(const int* __restrict__ seq_len, int* __restrict__ sections,
                            int* __restrict__ offsets, int* __restrict__ last_idx,
                            int nsess) {
  __shared__ int s1[1024];
  __shared__ int s2[1024];
  int t = threadIdx.x;
  int v1 = (t < nsess) ? sections[t] : 0;
  int v2 = (t < nsess) ? seq_len[t] : 0;
  s1[t] = v1; s2[t] = v2;
  for (int d = 1; d < 1024; d <<= 1) {
    __syncthreads();
    int a1 = (t >= d) ? s1[t - d] : 0;
    int a2 = (t >= d) ? s2[t - d] : 0;
    __syncthreads();
    s1[t] += a1; s2[t] += a2;
  }
  __syncthreads();
  if (t < nsess) {
    offsets[t] = s1[t] - v1;     // exclusive cumsum of sections
    last_idx[t] = s2[t] - 1;     // cumsum(sequence_len) - 1
  }
}

// ---- one SAN GEMM stage, 16-wave version: each wave owns a 16x16 tile ----
template<bool RELU, bool RESID, bool WACC>
__device__ __forceinline__ void gemm_stage16(const ushort* inA, const ushort* __restrict__ Wbf,
                                             const float* __restrict__ bias,
                                             float* accf, ushort* outB) {
  int t = threadIdx.x;
  int lane = t & 63, wid = t >> 6;       // 16 waves
  int la = lane & 15, g = lane >> 4;
  int col = wid * 16 + la;
  f32x4 acc = {0.f, 0.f, 0.f, 0.f};
#pragma unroll
  for (int kk = 0; kk < 8; ++kk) {
    short8 a = *(const short8*)&inA[swz(la, kk * 32 + g * 8)];
    short8 b = *(const short8*)&Wbf[col * HD + kk * 32 + g * 8];
    acc = __builtin_amdgcn_mfma_f32_16x16x32_bf16(a, b, acc, 0, 0, 0);
  }
  float bia = bias[col];
#pragma unroll
  for (int r = 0; r < 4; ++r) {
    int ro = g * 4 + r;
    float v = acc[r] + bia;
    if (RELU) v = fmaxf(v, 0.f);
    if (RESID) v += accf[ro * HD + col];
    if (WACC) accf[ro * HD + col] = v;
    outB[swz(ro, col)] = f2bf(v);
  }
}

__device__ __forceinline__ void stage_fence() {
  __syncthreads();
  __builtin_amdgcn_sched_barrier(0);
}

// -------- v_n + SAN x3 + s_h + y_hat (16 rows / block, 16 waves) ---------
__global__ __launch_bounds__(1024, 1) void sh_kernel(
    const float* __restrict__ node_emb, const float* __restrict__ emb_w,
    const float* __restrict__ itemset_len, const float* __restrict__ in_proj_b,
    const float* __restrict__ out_proj_b, const float* __restrict__ d1_b,
    const float* __restrict__ d2_b, const float* __restrict__ W3_b,
    const int* __restrict__ sequence, const int* __restrict__ cue,
    const int* __restrict__ sections, const int* __restrict__ offsets,
    const int* __restrict__ last_idx,
    const ushort* __restrict__ Wv_bf, const ushort* __restrict__ Po_bf,
    const ushort* __restrict__ d1_bf, const ushort* __restrict__ d2_bf,
    const ushort* __restrict__ W3_bf,
    ushort* __restrict__ sh_bf, float* __restrict__ y_hat, int group) {
  __shared__ float accf[16 * HD];
  __shared__ ushort vn_bf[16 * HD];
  __shared__ ushort bufA[16 * HD];
  __shared__ ushort bufB[16 * HD];
  int t = threadIdx.x;
  int b0 = blockIdx.x * 16;

  // ---- v_n: gather last-step itemset embedding (1 float4 per thread) ----
  {
    int r = t >> 6, cg = t & 63;         // row r, 64 threads/row, 4 floats each
    int sess = b0 + r;
    int li = last_idx[sess];
    float inv = 1.0f / itemset_len[li];
    int sec = sections[sess], off = offsets[sess];
    float4 s = {0.f, 0.f, 0.f, 0.f};
    for (int gi = 0; gi < group; ++gi) {
      int sq = sequence[li * group + gi];
      if (sq == sec) continue;           // padding row -> zero
      float4 v = *(const float4*)(node_emb + (size_t)(off + sq) * HD + cg * 4);
      s.x += v.x; s.y += v.y; s.z += v.z; s.w += v.w;
    }
    short4v u;
    u[0] = (short)f2bf(s.x * inv); u[1] = (short)f2bf(s.y * inv);
    u[2] = (short)f2bf(s.z * inv); u[3] = (short)f2bf(s.w * inv);
    *(short4v*)&vn_bf[swz(r, cg * 4)] = u;   // cg*4 % 8 in {0,4}: stays in chunk
  }
  stage_fence();

  // ---- 3 SAN blocks ----
  const ushort* cur = vn_bf;
#pragma unroll 1
  for (int sb = 0; sb < 3; ++sb) {
    gemm_stage16<false, false, false>(cur, Wv_bf, in_proj_b + 2 * HD, nullptr, bufA); // t1 = x@Wv^T+bv
    stage_fence();
    gemm_stage16<false, false, true>(bufA, Po_bf, out_proj_b, accf, bufB);            // attn (fp32 in accf)
    stage_fence();
    gemm_stage16<true, false, false>(bufB, d1_bf, d1_b, nullptr, bufA);               // t2 = relu(attn@d1^T+b1)
    stage_fence();
    gemm_stage16<false, true, false>(bufA, d2_bf, d2_b, accf, bufB);                  // x = attn + t2@d2^T+b2
    stage_fence();
    cur = bufB;
  }

  // ---- s_h = [v_n, s_g] @ W3^T + b3 (K=512), 1 col-tile per wave ----
  {
    int lane = t & 63, wid = t >> 6;
    int la = lane & 15, g = lane >> 4;
    int col = wid * 16 + la;
    f32x4 acc = {0.f, 0.f, 0.f, 0.f};
#pragma unroll
    for (int kk = 0; kk < 16; ++kk) {
      const ushort* src = (kk < 8) ? vn_bf : cur;
      short8 a = *(const short8*)&src[swz(la, (kk & 7) * 32 + g * 8)];
      short8 b = *(const short8*)&W3_bf[col * 2 * HD + kk * 32 + g * 8];
      acc = __builtin_amdgcn_mfma_f32_16x16x32_bf16(a, b, acc, 0, 0, 0);
    }
    float bia = W3_b[col];
#pragma unroll
    for (int r = 0; r < 4; ++r) {
      int ro = g * 4 + r;
      float v = acc[r] + bia;
      accf[ro * HD + col] = v;
      sh_bf[(size_t)(b0 + ro) * HD + col] = f2bf(v);
    }
  }
  stage_fence();

  // ---- y_hat = dot(s_h, emb[cue]) in fp32; one wave per row ----
  {
    int r = t >> 6, lane = t & 63;
    const float4 er = *(const float4*)(emb_w + (size_t)cue[b0 + r] * HD + lane * 4);
    const float* ar = &accf[r * HD + lane * 4];
    float p = ar[0] * er.x + ar[1] * er.y + ar[2] * er.z + ar[3] * er.w;
#pragma unroll
    for (int off = 32; off >= 1; off >>= 1) p += __shfl_down(p, off, 64);
    if (lane == 0) y_hat[b0 + r] = p;
  }
}

// ---------------- all_scores = s_h @ emb^T  (block owns 64 vocab rows) ---
// Round-5 fix: old epilogue stored 64B runs (16 lanes x 4B) at 200KB row
// stride, 16 scattered rows per instruction -> ~1.8TB/s effective (score
// ~145us by subtraction). New epilogue stages each wave's 16x64 fp32 tile
// in padded LDS (wave-private rows, no barrier), then does wave-wide 256B
// contiguous nontemporal stores (streaming: keep L2 for emb/sh).
__global__ __launch_bounds__(256) void score_kernel(
    const ushort* __restrict__ sh_bf, const float* __restrict__ emb_w,
    float* __restrict__ scores, int nrows, int V) {
  __shared__ ushort ebuf[64 * HD];
  __shared__ float obuf[64][65];         // +1 pad: store-phase reads conflict-free
  int t = threadIdx.x;
  int c0 = blockIdx.x * 64;
  // stage emb rows c0..c0+63 as bf16, XOR-swizzled
#pragma unroll
  for (int i = 0; i < 8; ++i) {
    int c = t + i * 256;           // chunk id, 64 rows * 32 chunks
    int row = c >> 5, q = c & 31;
    if (c0 + row < V) {
      const float4* src = (const float4*)(emb_w + (size_t)(c0 + row) * HD + q * 8);
      float4 v0 = src[0], v1 = src[1];
      short8 u;
      u[0] = (short)f2bf(v0.x); u[1] = (short)f2bf(v0.y);
      u[2] = (short)f2bf(v0.z); u[3] = (short)f2bf(v0.w);
      u[4] = (short)f2bf(v1.x); u[5] = (short)f2bf(v1.y);
      u[6] = (short)f2bf(v1.z); u[7] = (short)f2bf(v1.w);
      *(short8*)&ebuf[row * 256 + ((q ^ (row & 7)) * 8)] = u;
    }
  }
  __syncthreads();

  int lane = t & 63, wid = t >> 6;
  int la = lane & 15, g = lane >> 4;
  int nrb = nrows >> 6;
  int cg = c0 + lane;                    // store-phase column of this lane
  bool cok = cg < V;
  for (int rb = 0; rb < nrb; ++rb) {
    int r0 = rb * 64 + wid * 16;
    const ushort* arow = sh_bf + (size_t)(r0 + la) * HD;
    short8 a[8];
#pragma unroll
    for (int kk = 0; kk < 8; ++kk) a[kk] = *(const short8*)&arow[kk * 32 + g * 8];
    f32x4 acc[4] = {{0.f,0.f,0.f,0.f},{0.f,0.f,0.f,0.f},{0.f,0.f,0.f,0.f},{0.f,0.f,0.f,0.f}};
#pragma unroll
    for (int kk = 0; kk < 8; ++kk) {
#pragma unroll
      for (int ct = 0; ct < 4; ++ct) {
        int brow = ct * 16 + la;
        short8 b = *(const short8*)&ebuf[brow * 256 + (((kk * 4 + g) ^ (brow & 7)) * 8)];
        acc[ct] = __builtin_amdgcn_mfma_f32_16x16x32_bf16(a[kk], b, acc[ct], 0, 0, 0);
      }
    }
    // stage result tile in LDS (rows wid*16..wid*16+15 are wave-private)
#pragma unroll
    for (int ct = 0; ct < 4; ++ct)
#pragma unroll
      for (int r = 0; r < 4; ++r)
        obuf[wid * 16 + g * 4 + r][ct * 16 + la] = acc[ct][r];
    // wave-wide 256B contiguous nontemporal stores, one output row at a time
#pragma unroll
    for (int i = 0; i < 16; ++i) {
      int row = wid * 16 + i;
      float v = obuf[row][lane];
      if (cok)
        __builtin_nontemporal_store(v, &scores[(size_t)(rb * 64 + row) * V + cg]);
    }
  }
}

extern "C" void kernel_launch(void* const* d_in, const int* in_sizes, int n_in,
                              void* d_out, int out_size, void* d_ws, size_t ws_size,
                              hipStream_t stream) {
  const float* node_emb   = (const float*)d_in[0];
  const float* emb_w      = (const float*)d_in[1];
  const float* itemset_len= (const float*)d_in[2];
  const float* in_proj_w  = (const float*)d_in[3];
  const float* in_proj_b  = (const float*)d_in[4];
  const float* out_proj_w = (const float*)d_in[5];
  const float* out_proj_b = (const float*)d_in[6];
  const float* d1_w       = (const float*)d_in[7];
  const float* d1_b       = (const float*)d_in[8];
  const float* d2_w       = (const float*)d_in[9];
  const float* d2_b       = (const float*)d_in[10];
  const float* W3_w       = (const float*)d_in[11];
  const float* W3_b       = (const float*)d_in[12];
  const int*   batch      = (const int*)d_in[13];
  const int*   sequence   = (const int*)d_in[14];
  const int*   seq_len    = (const int*)d_in[15];
  const int*   cue        = (const int*)d_in[16];

  int total_nodes = in_sizes[0] / HD;
  int V           = in_sizes[1] / HD;
  int nsess       = in_sizes[15];
  int total_steps = in_sizes[2];
  int group       = in_sizes[14] / total_steps;

  char* ws = (char*)d_ws;
  int* sections   = (int*)(ws);
  int* offsets    = (int*)(ws + 4096);
  int* last_idx   = (int*)(ws + 8192);
  ushort* sh_bf   = (ushort*)(ws + 16384);                 // nsess*256 bf16
  ushort* Wv_bf   = (ushort*)(ws + 16384 + 524288);
  ushort* Po_bf   = Wv_bf + HD * HD;
  ushort* d1_bf   = Po_bf + HD * HD;
  ushort* d2_bf   = d1_bf + HD * HD;
  ushort* W3_bf   = d2_bf + HD * HD;

  float* y_hat  = (float*)d_out;
  float* scores = (float*)d_out + nsess;

  zero_kernel<<<1, 1024, 0, stream>>>(sections, nsess);
  prep1_kernel<<<512, 256, 0, stream>>>(batch, total_nodes, sections,
                                        in_proj_w, out_proj_w, d1_w, d2_w, W3_w,
                                        Wv_bf, Po_bf, d1_bf, d2_bf, W3_bf);
  scan_kernel<<<1, 1024, 0, stream>>>(seq_len, sections, offsets, last_idx, nsess);
  sh_kernel<<<nsess / 16, 1024, 0, stream>>>(node_emb, emb_w, itemset_len, in_proj_b,
                                             out_proj_b, d1_b, d2_b, W3_b,
                                             sequence, cue, sections, offsets, last_idx,
                                             Wv_bf, Po_bf, d1_bf, d2_bf, W3_bf,
                                             sh_bf, y_hat, group);
  score_kernel<<<(V + 63) / 64, 256, 0, stream>>>(sh_bf, emb_w, scores, nsess, V);
}